// Round 7
// baseline (336.903 us; speedup 1.0000x reference)
//
#include <hip/hip_runtime.h>
#include <hip/hip_bf16.h>

#define N_NODES 2048
#define EMB 768
#define NH 8
#define DH 96
#define ALPHA 0.2f
#define SCALE 0.10206207261596575f  // 96^-0.5
#define NGMAX 192
#define NB 256                      // grid blocks (1 per CU, guaranteed co-resident)
#define WSZ (EMB * EMB)

typedef __bf16 bf16x8 __attribute__((ext_vector_type(8)));
typedef float f32x4 __attribute__((ext_vector_type(4)));
typedef __attribute__((address_space(3))) unsigned int lds_u32;
typedef __attribute__((address_space(1))) const unsigned int glb_u32;

union pack4 { ushort4 u; __hip_bfloat16 h[4]; };

struct AttnLds {                    // 46,080 B
    int   jb[NGMAX];
    int   qg[NGMAX];
    float s2g[NGMAX];
    float s1g[NGMAX][9];            // pad 9 breaks stride-8 conflicts
    float Whg[NGMAX][48];
};

// software grid barrier: monotonic counter, agent-scope release/acquire
__device__ __forceinline__ void grid_barrier(int* bar, int target)
{
    __syncthreads();
    if (threadIdx.x == 0) {
        __threadfence();  // release: flush this XCD's L2
        __hip_atomic_fetch_add(bar, 1, __ATOMIC_ACQ_REL, __HIP_MEMORY_SCOPE_AGENT);
        while (__hip_atomic_load(bar, __ATOMIC_ACQUIRE, __HIP_MEMORY_SCOPE_AGENT) < target)
            __builtin_amdgcn_s_sleep(1);
        __threadfence();  // acquire: invalidate stale lines
    }
    __syncthreads();
}

// stage a 64x128 bf16 tile into LDS with 16B-chunk XOR swizzle (chunk (row,cb) at
// index row*16 + (cb ^ (row&15))); dest is wave-uniform base + lane*16 as required.
__device__ __forceinline__ void stage128(
    const __hip_bfloat16* __restrict__ src, int row0, int k0,
    __hip_bfloat16* lds, int wave, int lane)
{
#pragma unroll
    for (int i = 0; i < 4; i++) {
        const int c0 = wave * 256 + i * 64;
        const int c = c0 + lane;
        const int row = c >> 4;
        const int cb = (c & 15) ^ (row & 15);
        const __hip_bfloat16* g = src + (size_t)(row0 + row) * EMB + k0 + cb * 8;
        __builtin_amdgcn_global_load_lds((glb_u32*)g, (lds_u32*)(lds + c0 * 8), 16, 0, 0);
    }
}

// grid-strided 64x64-tile GEMM phase: C = A1@B1^T [+ A2@B2^T] [+ bias1+bias2]
// BK=128 double-buffered (64 KB LDS), 384 tiles over NB blocks.
__device__ __forceinline__ void gemm_tiles(
    const __hip_bfloat16* __restrict__ A1, const __hip_bfloat16* __restrict__ B1, int ns1,
    const __hip_bfloat16* __restrict__ A2, const __hip_bfloat16* __restrict__ B2, int ns2,
    const float* __restrict__ bias1, const float* __restrict__ bias2,
    float* __restrict__ Cf, __hip_bfloat16* sm)
{
    const int t = threadIdx.x;
    const int lane = t & 63, wave = t >> 6;
    const int wm = wave >> 1, wn = wave & 1;
    const int l15 = lane & 15, quad = lane >> 4;
    const int NS = ns1 + ns2;
    const int rA = wm * 32 + l15, rB = wn * 32 + l15;

    for (int T = blockIdx.x; T < 384; T += NB) {
        const int bm = (T & 31) * 64, bn = (T >> 5) * 64;
        f32x4 acc00 = {0.f,0.f,0.f,0.f}, acc01 = {0.f,0.f,0.f,0.f};
        f32x4 acc10 = {0.f,0.f,0.f,0.f}, acc11 = {0.f,0.f,0.f,0.f};

        __syncthreads();                      // smem reuse guard across T
        stage128(A1, bm, 0, sm, wave, lane);
        stage128(B1, bn, 0, sm + 8192, wave, lane);

        for (int s = 0; s < NS; s++) {
            __syncthreads();                  // vmcnt drain: stage s resident
            if (s + 1 < NS) {
                const int sn = s + 1;
                const __hip_bfloat16* As = (sn < ns1) ? A1 : A2;
                const __hip_bfloat16* Bs = (sn < ns1) ? B1 : B2;
                const int k0 = ((sn < ns1) ? sn : sn - ns1) * 128;
                __hip_bfloat16* dst = sm + (sn & 1) * 16384;
                stage128(As, bm, k0, dst, wave, lane);
                stage128(Bs, bn, k0, dst + 8192, wave, lane);
            }
            const __hip_bfloat16* At = sm + (s & 1) * 16384;
            const __hip_bfloat16* Bt = At + 8192;
#pragma unroll
            for (int ks = 0; ks < 4; ks++) {
                const int cq = ks * 4 + quad;
                bf16x8 a0 = *(const bf16x8*)(At + (size_t)(rA * 16        + (cq ^ l15)) * 8);
                bf16x8 a1 = *(const bf16x8*)(At + (size_t)((rA + 16) * 16 + (cq ^ l15)) * 8);
                bf16x8 b0 = *(const bf16x8*)(Bt + (size_t)(rB * 16        + (cq ^ l15)) * 8);
                bf16x8 b1 = *(const bf16x8*)(Bt + (size_t)((rB + 16) * 16 + (cq ^ l15)) * 8);
                acc00 = __builtin_amdgcn_mfma_f32_16x16x32_bf16(a0, b0, acc00, 0, 0, 0);
                acc01 = __builtin_amdgcn_mfma_f32_16x16x32_bf16(a0, b1, acc01, 0, 0, 0);
                acc10 = __builtin_amdgcn_mfma_f32_16x16x32_bf16(a1, b0, acc10, 0, 0, 0);
                acc11 = __builtin_amdgcn_mfma_f32_16x16x32_bf16(a1, b1, acc11, 0, 0, 0);
            }
        }

        const int col0 = bn + wn * 32 + l15;
        const int col1 = col0 + 16;
        float bv0 = 0.f, bv1 = 0.f;
        if (bias1 != nullptr) {
            bv0 = bias1[col0] + bias2[col0];
            bv1 = bias1[col1] + bias2[col1];
        }
        const int r0 = bm + wm * 32 + quad * 4;
#pragma unroll
        for (int r = 0; r < 4; r++) {
            const int row0 = r0 + r, row1 = r0 + 16 + r;
            Cf[(size_t)row0 * EMB + col0] = acc00[r] + bv0;
            Cf[(size_t)row0 * EMB + col1] = acc01[r] + bv1;
            Cf[(size_t)row1 * EMB + col0] = acc10[r] + bv0;
            Cf[(size_t)row1 * EMB + col1] = acc11[r] + bv1;
        }
    }
}

// zero cnt[32] + barrier (ws is 0xAA-poisoned before every launch)
__global__ void zero_kernel(int* p)
{
    if (threadIdx.x < 64) p[threadIdx.x] = 0;
}

// ---------------------------------------------------------------- the whole layer
__global__ __launch_bounds__(256) void mega_kernel(
    const float* __restrict__ eh, const float* __restrict__ er, const float* __restrict__ et,
    const int* __restrict__ h_id, const float* __restrict__ W_w, const float* __restrict__ av,
    const float* __restrict__ proj_w, const float* __restrict__ proj_b,
    const float* __restrict__ skip_w, const float* __restrict__ skip_b,
    __hip_bfloat16* __restrict__ e, float* __restrict__ Wh, __hip_bfloat16* __restrict__ at,
    __hip_bfloat16* __restrict__ Wb, __hip_bfloat16* __restrict__ Pb, __hip_bfloat16* __restrict__ Sb,
    float* __restrict__ s1, float* __restrict__ s2,
    int* __restrict__ cnt, int* __restrict__ bar, int* __restrict__ lists,
    float* __restrict__ out)
{
    __shared__ __attribute__((aligned(16))) char smem[65536];
    const int t = threadIdx.x;
    const int gtid = blockIdx.x * 256 + t;

    // ---- phase 0: concat-cast e, cast weights, build group lists
    for (int c4 = gtid; c4 < 393216; c4 += NB * 256) {
        int idx = c4 * 4, i = idx / EMB, c = idx % EMB;
        const float* src = (c < 256) ? eh + i * 256 + c
                         : (c < 512) ? er + i * 256 + (c - 256)
                                     : et + i * 256 + (c - 512);
        float4 v = *reinterpret_cast<const float4*>(src);
        pack4 p;
        p.h[0] = __float2bfloat16(v.x); p.h[1] = __float2bfloat16(v.y);
        p.h[2] = __float2bfloat16(v.z); p.h[3] = __float2bfloat16(v.w);
        *reinterpret_cast<ushort4*>(e + (size_t)i * EMB + c) = p.u;
    }
    for (int c4 = gtid; c4 < 442368; c4 += NB * 256) {
        int idx = c4 * 4;
        const float* src; __hip_bfloat16* dst;
        if (idx < WSZ)          { src = W_w    + idx;           dst = Wb + idx; }
        else if (idx < 2 * WSZ) { src = proj_w + idx - WSZ;     dst = Pb + idx - WSZ; }
        else                    { src = skip_w + idx - 2 * WSZ; dst = Sb + idx - 2 * WSZ; }
        float4 v = *reinterpret_cast<const float4*>(src);
        pack4 p;
        p.h[0] = __float2bfloat16(v.x); p.h[1] = __float2bfloat16(v.y);
        p.h[2] = __float2bfloat16(v.z); p.h[3] = __float2bfloat16(v.w);
        *reinterpret_cast<ushort4*>(dst) = p.u;
    }
    if (gtid < N_NODES) {
        int g = h_id[gtid];
        int p = atomicAdd(&cnt[g], 1);
        lists[g * N_NODES + p] = gtid;
    }

    grid_barrier(bar, NB);

    // ---- phase 1: Wh = e @ W_w^T
    gemm_tiles(e, Wb, 6, nullptr, nullptr, 0, nullptr, nullptr, Wh, (__hip_bfloat16*)smem);

    grid_barrier(bar, 2 * NB);

    // ---- phase 2: s1/s2 = Wh . a1/a2
    if (gtid < N_NODES * NH) {
        int i = gtid >> 3, h = gtid & 7;
        const float* wr = Wh + (size_t)i * EMB + h * DH;
        float acc1 = 0.f, acc2 = 0.f;
        for (int d = 0; d < DH; d++) {
            float w = wr[d];
            acc1 += w * av[d];
            acc2 += w * av[DH + d];
        }
        s1[gtid] = acc1;
        s2[gtid] = acc2;
    }

    grid_barrier(bar, 3 * NB);

    // ---- phase 3: group-masked softmax attention + PV
    {
        AttnLds& AL = *reinterpret_cast<AttnLds*>(smem);
        const int lane = t & 63, wave = t >> 6;
        for (int v = blockIdx.x; v < 512; v += NB) {
            __syncthreads();                          // smem reuse guard
            const int g = v & 31, h = (v >> 5) & 7, dh = v >> 8;
            const int ng = min(cnt[g], NGMAX);
            const int* gl = lists + g * N_NODES;
            for (int j = t; j < ng; j += 256) {
                int node = gl[j];
                AL.jb[j]  = node;
                AL.qg[j]  = node >> 8;
                AL.s2g[j] = s2[node * 8 + h];
                float4 v0 = *reinterpret_cast<const float4*>(s1 + node * 8);
                float4 v1 = *reinterpret_cast<const float4*>(s1 + node * 8 + 4);
                AL.s1g[j][0] = v0.x; AL.s1g[j][1] = v0.y; AL.s1g[j][2] = v0.z; AL.s1g[j][3] = v0.w;
                AL.s1g[j][4] = v1.x; AL.s1g[j][5] = v1.y; AL.s1g[j][6] = v1.z; AL.s1g[j][7] = v1.w;
            }
            __syncthreads();
            for (int idx = t; idx < ng * 12; idx += 256) {
                int jc = idx / 12, dq = idx % 12;
                float4 v4 = *reinterpret_cast<const float4*>(
                    Wh + (size_t)AL.jb[jc] * EMB + h * DH + dh * 48 + dq * 4);
                *reinterpret_cast<float4*>(&AL.Whg[jc][dq * 4]) = v4;
            }
            __syncthreads();
            for (int n0 = 0; n0 < ng; n0 += 64) {
                const int tn = n0 + lane;
                if (tn < ng) {
                    float m = -1e30f;
                    for (int j = 0; j < ng; j++) {
                        float x = AL.s1g[tn][AL.qg[j]] + AL.s2g[j];
                        float ev = (x >= 0.f ? x : ALPHA * x) * SCALE;
                        m = fmaxf(m, ev);
                    }
                    float S = 0.f;
                    for (int j = 0; j < ng; j++) {
                        float x = AL.s1g[tn][AL.qg[j]] + AL.s2g[j];
                        float ev = (x >= 0.f ? x : ALPHA * x) * SCALE;
                        S += __expf(ev - m);
                    }
                    const float ri = 1.f / S;
                    float acc[12];
#pragma unroll
                    for (int d = 0; d < 12; d++) acc[d] = 0.f;
                    for (int j = 0; j < ng; j++) {
                        float x = AL.s1g[tn][AL.qg[j]] + AL.s2g[j];
                        float ev = (x >= 0.f ? x : ALPHA * x) * SCALE;
                        float p = __expf(ev - m) * ri;
#pragma unroll
                        for (int d = 0; d < 12; d++) acc[d] += p * AL.Whg[j][wave * 12 + d];
                    }
                    __hip_bfloat16* po = at + (size_t)AL.jb[tn] * EMB + h * DH + dh * 48 + wave * 12;
#pragma unroll
                    for (int d = 0; d < 12; d += 4) {
                        pack4 pk;
                        pk.h[0] = __float2bfloat16(acc[d]);
                        pk.h[1] = __float2bfloat16(acc[d + 1]);
                        pk.h[2] = __float2bfloat16(acc[d + 2]);
                        pk.h[3] = __float2bfloat16(acc[d + 3]);
                        *reinterpret_cast<ushort4*>(po + d) = pk.u;
                    }
                }
            }
        }
    }

    grid_barrier(bar, 4 * NB);

    // ---- phase 4: out = at @ proj_w^T + e @ skip_w^T + (proj_b + skip_b)
    gemm_tiles(at, Pb, 6, e, Sb, 6, proj_b, skip_b, out, (__hip_bfloat16*)smem);
}

// ---------------------------------------------------------------- launch
extern "C" void kernel_launch(void* const* d_in, const int* in_sizes, int n_in,
                              void* d_out, int out_size, void* d_ws, size_t ws_size,
                              hipStream_t stream)
{
    const float* eh     = (const float*)d_in[0];
    const float* er     = (const float*)d_in[1];
    const float* et     = (const float*)d_in[2];
    const int*   h_id   = (const int*)d_in[3];
    const float* W_w    = (const float*)d_in[4];
    const float* a      = (const float*)d_in[5];
    const float* proj_w = (const float*)d_in[6];
    const float* proj_b = (const float*)d_in[7];
    const float* skip_w = (const float*)d_in[8];
    const float* skip_b = (const float*)d_in[9];
    float* out = (float*)d_out;   // reference output dtype is f32

    char* ws = (char*)d_ws;
    __hip_bfloat16* e_ws   = (__hip_bfloat16*)(ws);
    float*          Wh_ws  = (float*)(ws + 3145728);
    __hip_bfloat16* at_ws  = (__hip_bfloat16*)(ws + 9437184);
    __hip_bfloat16* Wb_ws  = (__hip_bfloat16*)(ws + 12582912);
    __hip_bfloat16* Pb_ws  = (__hip_bfloat16*)(ws + 13762560);
    __hip_bfloat16* Sb_ws  = (__hip_bfloat16*)(ws + 14942208);
    float*          s1_ws  = (float*)(ws + 16121856);
    float*          s2_ws  = (float*)(ws + 16187392);
    int*            cnt_ws = (int*)(ws + 16252928);
    int*            bar_ws = (int*)(ws + 16253056);
    int*            lst_ws = (int*)(ws + 16253184);

    zero_kernel<<<1, 64, 0, stream>>>(cnt_ws);   // zeroes cnt[32] + bar (256 B)

    mega_kernel<<<NB, 256, 0, stream>>>(
        eh, er, et, h_id, W_w, a, proj_w, proj_b, skip_w, skip_b,
        e_ws, Wh_ws, at_ws, Wb_ws, Pb_ws, Sb_ws, s1_ws, s2_ws,
        cnt_ws, bar_ws, lst_ws, out);
}

// Round 8
// 136.659 us; speedup vs baseline: 2.4653x; 2.4653x over previous
//
#include <hip/hip_runtime.h>
#include <hip/hip_bf16.h>

#define N_NODES 2048
#define EMB 768
#define NH 8
#define DH 96
#define ALPHA 0.2f
#define SCALE 0.10206207261596575f  // 96^-0.5
#define NGMAX 192
#define WSZ (EMB * EMB)

typedef __bf16 bf16x8 __attribute__((ext_vector_type(8)));
typedef float f32x4 __attribute__((ext_vector_type(4)));
typedef __attribute__((address_space(3))) unsigned int lds_u32;
typedef __attribute__((address_space(1))) const unsigned int glb_u32;

union pack4 { ushort4 u; __hip_bfloat16 h[4]; };

// ---------------------------------------------------------------- prep: concat-cast e + cast 3 weights + zero cnt
__global__ __launch_bounds__(256) void prep_kernel(
    const float* __restrict__ eh, const float* __restrict__ er, const float* __restrict__ et,
    const float* __restrict__ W0, const float* __restrict__ W1, const float* __restrict__ W2,
    __hip_bfloat16* __restrict__ e, __hip_bfloat16* __restrict__ o0,
    __hip_bfloat16* __restrict__ o1, __hip_bfloat16* __restrict__ o2, int* __restrict__ cnt)
{
    const int b = blockIdx.x;
    const int gtid = b * 256 + threadIdx.x;
    if (gtid < 32) cnt[gtid] = 0;
    const float* src;
    __hip_bfloat16* dst;
    if (b < 1536) {                       // e = concat(eh,er,et)
        int idx = gtid * 4;
        int i = idx / EMB, c = idx % EMB;
        if (c < 256)      src = eh + i * 256 + c;
        else if (c < 512) src = er + i * 256 + (c - 256);
        else              src = et + i * 256 + (c - 512);
        dst = e + (size_t)i * EMB + c;
    } else {                              // three 768x768 weights
        int idx = (gtid - 1536 * 256) * 4;
        if (idx < WSZ)          { src = W0 + idx;           dst = o0 + idx; }
        else if (idx < 2 * WSZ) { src = W1 + idx - WSZ;     dst = o1 + idx - WSZ; }
        else                    { src = W2 + idx - 2 * WSZ; dst = o2 + idx - 2 * WSZ; }
    }
    float4 v = *reinterpret_cast<const float4*>(src);
    pack4 p;
    p.h[0] = __float2bfloat16(v.x);
    p.h[1] = __float2bfloat16(v.y);
    p.h[2] = __float2bfloat16(v.z);
    p.h[3] = __float2bfloat16(v.w);
    *reinterpret_cast<ushort4*>(dst) = p.u;
}

// ---------------------------------------------------------------- BK=128 async-staged MFMA GEMM
// C = A1@B1^T [+ A2@B2^T] [+ bias1+bias2], row-major ld=EMB, M=2048, N=EMB.
// 64x64 tile/block, 4 waves (2x2), BK=128 double-buffer (64 KB LDS),
// global_load_lds width=16, 16B-chunk XOR swizzle: chunk (row,cb) at row*16+(cb^(row&15)).
// (This K-loop shape was correctness-proven inside R7's mega kernel.)
__device__ __forceinline__ void stage128(
    const __hip_bfloat16* __restrict__ src, int row0, int k0,
    __hip_bfloat16* lds, int wave, int lane)
{
#pragma unroll
    for (int i = 0; i < 4; i++) {
        const int c0 = wave * 256 + i * 64;
        const int c = c0 + lane;
        const int row = c >> 4;
        const int cb = (c & 15) ^ (row & 15);
        const __hip_bfloat16* g = src + (size_t)(row0 + row) * EMB + k0 + cb * 8;
        __builtin_amdgcn_global_load_lds((glb_u32*)g, (lds_u32*)(lds + c0 * 8), 16, 0, 0);
    }
}

__global__ __launch_bounds__(256) void gemm_nt_kernel(
    const __hip_bfloat16* __restrict__ A1, const __hip_bfloat16* __restrict__ B1, int ns1,
    const __hip_bfloat16* __restrict__ A2, const __hip_bfloat16* __restrict__ B2, int ns2,
    const float* __restrict__ bias1, const float* __restrict__ bias2,
    float* __restrict__ Cf)
{
    __shared__ __attribute__((aligned(16))) __hip_bfloat16 sm[2][2][8192]; // [buf][A/B][64x128]

    const int t = threadIdx.x;
    const int lane = t & 63, wave = t >> 6;
    const int wm = wave >> 1, wn = wave & 1;
    const int bm = blockIdx.y * 64, bn = blockIdx.x * 64;
    const int l15 = lane & 15, quad = lane >> 4;
    const int NS = ns1 + ns2;
    const int rA = wm * 32 + l15, rB = wn * 32 + l15;

    f32x4 acc00 = {0.f,0.f,0.f,0.f}, acc01 = {0.f,0.f,0.f,0.f};
    f32x4 acc10 = {0.f,0.f,0.f,0.f}, acc11 = {0.f,0.f,0.f,0.f};

    stage128(A1, bm, 0, &sm[0][0][0], wave, lane);
    stage128(B1, bn, 0, &sm[0][1][0], wave, lane);

    for (int s = 0; s < NS; s++) {
        __syncthreads();                  // vmcnt drain: stage s resident
        if (s + 1 < NS) {
            const int sn = s + 1;
            const __hip_bfloat16* As = (sn < ns1) ? A1 : A2;
            const __hip_bfloat16* Bs = (sn < ns1) ? B1 : B2;
            const int k0 = ((sn < ns1) ? sn : sn - ns1) * 128;
            stage128(As, bm, k0, &sm[sn & 1][0][0], wave, lane);
            stage128(Bs, bn, k0, &sm[sn & 1][1][0], wave, lane);
        }
        const __hip_bfloat16* At = &sm[s & 1][0][0];
        const __hip_bfloat16* Bt = &sm[s & 1][1][0];
#pragma unroll
        for (int ks = 0; ks < 4; ks++) {
            const int cq = ks * 4 + quad;
            bf16x8 a0 = *(const bf16x8*)(At + (size_t)(rA * 16        + (cq ^ l15)) * 8);
            bf16x8 a1 = *(const bf16x8*)(At + (size_t)((rA + 16) * 16 + (cq ^ l15)) * 8);
            bf16x8 b0 = *(const bf16x8*)(Bt + (size_t)(rB * 16        + (cq ^ l15)) * 8);
            bf16x8 b1 = *(const bf16x8*)(Bt + (size_t)((rB + 16) * 16 + (cq ^ l15)) * 8);
            acc00 = __builtin_amdgcn_mfma_f32_16x16x32_bf16(a0, b0, acc00, 0, 0, 0);
            acc01 = __builtin_amdgcn_mfma_f32_16x16x32_bf16(a0, b1, acc01, 0, 0, 0);
            acc10 = __builtin_amdgcn_mfma_f32_16x16x32_bf16(a1, b0, acc10, 0, 0, 0);
            acc11 = __builtin_amdgcn_mfma_f32_16x16x32_bf16(a1, b1, acc11, 0, 0, 0);
        }
    }

    const int col0 = bn + wn * 32 + l15;
    const int col1 = col0 + 16;
    float bv0 = 0.f, bv1 = 0.f;
    if (bias1 != nullptr) {
        bv0 = bias1[col0] + bias2[col0];
        bv1 = bias1[col1] + bias2[col1];
    }
    const int r0 = bm + wm * 32 + quad * 4;
#pragma unroll
    for (int r = 0; r < 4; r++) {
        const int row0 = r0 + r, row1 = r0 + 16 + r;
        Cf[(size_t)row0 * EMB + col0] = acc00[r] + bv0;
        Cf[(size_t)row0 * EMB + col1] = acc01[r] + bv1;
        Cf[(size_t)row1 * EMB + col0] = acc10[r] + bv0;
        Cf[(size_t)row1 * EMB + col1] = acc11[r] + bv1;
    }
}

// ---------------------------------------------------------------- s1/s2 + group lists (fused)
__global__ __launch_bounds__(256) void s12g_kernel(
    const float* __restrict__ Wh, const float* __restrict__ a,
    float* __restrict__ s1, float* __restrict__ s2,
    const int* __restrict__ h_id, int* __restrict__ cnt, int* __restrict__ lists)
{
    int gid = blockIdx.x * 256 + threadIdx.x;  // [0, N*NH)
    if (gid < N_NODES) {
        int g = h_id[gid];
        int p = atomicAdd(&cnt[g], 1);
        lists[g * N_NODES + p] = gid;
    }
    int i = gid >> 3, h = gid & 7;
    const float* wr = Wh + (size_t)i * EMB + h * DH;
    float acc1 = 0.f, acc2 = 0.f;
    for (int d = 0; d < DH; d++) {
        float w = wr[d];
        acc1 += w * a[d];
        acc2 += w * a[DH + d];
    }
    s1[gid] = acc1;
    s2[gid] = acc2;
}

// ---------------------------------------------------------------- attention: block per (group, head, col-half)
__global__ __launch_bounds__(256) void attn_kernel(
    const float* __restrict__ Wh, const float* __restrict__ s1, const float* __restrict__ s2,
    const int* __restrict__ cnt, const int* __restrict__ lists,
    __hip_bfloat16* __restrict__ out)
{
    const int g  = blockIdx.x & 31;
    const int h  = (blockIdx.x >> 5) & 7;
    const int dh = blockIdx.x >> 8;          // 0/1 -> cols [dh*48, dh*48+48)
    const int t  = threadIdx.x;

    __shared__ int   jb[NGMAX];
    __shared__ int   qg[NGMAX];
    __shared__ float s2g[NGMAX];
    __shared__ float s1g[NGMAX][9];          // pad 9: stride-8 would 16-way conflict
    __shared__ float Whg[NGMAX][48];

    const int ng = min(cnt[g], NGMAX);
    const int* gl = lists + g * N_NODES;

    for (int j = t; j < ng; j += 256) {
        int node = gl[j];
        jb[j]  = node;
        qg[j]  = node >> 8;
        s2g[j] = s2[node * 8 + h];
        float4 v0 = *reinterpret_cast<const float4*>(s1 + node * 8);
        float4 v1 = *reinterpret_cast<const float4*>(s1 + node * 8 + 4);
        s1g[j][0] = v0.x; s1g[j][1] = v0.y; s1g[j][2] = v0.z; s1g[j][3] = v0.w;
        s1g[j][4] = v1.x; s1g[j][5] = v1.y; s1g[j][6] = v1.z; s1g[j][7] = v1.w;
    }
    __syncthreads();
    for (int idx = t; idx < ng * 12; idx += 256) {
        int jc = idx / 12, dq = idx % 12;
        float4 v = *reinterpret_cast<const float4*>(
            Wh + (size_t)jb[jc] * EMB + h * DH + dh * 48 + dq * 4);
        *reinterpret_cast<float4*>(&Whg[jc][dq * 4]) = v;
    }
    __syncthreads();

    if (t < ng) {
        float m = -1e30f;
        for (int j = 0; j < ng; j++) {
            float x = s1g[t][qg[j]] + s2g[j];
            float ev = (x >= 0.f ? x : ALPHA * x) * SCALE;
            m = fmaxf(m, ev);
        }
        float S = 0.f;
        for (int j = 0; j < ng; j++) {
            float x = s1g[t][qg[j]] + s2g[j];
            float ev = (x >= 0.f ? x : ALPHA * x) * SCALE;
            S += __expf(ev - m);
        }
        const float ri = 1.f / S;

        float acc[48];
#pragma unroll
        for (int d = 0; d < 48; d++) acc[d] = 0.f;
        for (int j = 0; j < ng; j++) {
            float x = s1g[t][qg[j]] + s2g[j];
            float ev = (x >= 0.f ? x : ALPHA * x) * SCALE;
            float p = __expf(ev - m) * ri;
#pragma unroll
            for (int d = 0; d < 48; d++) acc[d] += p * Whg[j][d];
        }
        __hip_bfloat16* po = out + (size_t)jb[t] * EMB + h * DH + dh * 48;
#pragma unroll
        for (int d = 0; d < 48; d += 4) {
            pack4 pk;
            pk.h[0] = __float2bfloat16(acc[d]);
            pk.h[1] = __float2bfloat16(acc[d + 1]);
            pk.h[2] = __float2bfloat16(acc[d + 2]);
            pk.h[3] = __float2bfloat16(acc[d + 3]);
            *reinterpret_cast<ushort4*>(po + d) = pk.u;
        }
    }
}

// ---------------------------------------------------------------- launch
extern "C" void kernel_launch(void* const* d_in, const int* in_sizes, int n_in,
                              void* d_out, int out_size, void* d_ws, size_t ws_size,
                              hipStream_t stream)
{
    const float* eh     = (const float*)d_in[0];
    const float* er     = (const float*)d_in[1];
    const float* et     = (const float*)d_in[2];
    const int*   h_id   = (const int*)d_in[3];
    const float* W_w    = (const float*)d_in[4];
    const float* a      = (const float*)d_in[5];
    const float* proj_w = (const float*)d_in[6];
    const float* proj_b = (const float*)d_in[7];
    const float* skip_w = (const float*)d_in[8];
    const float* skip_b = (const float*)d_in[9];
    float* out = (float*)d_out;   // reference output dtype is f32

    char* ws = (char*)d_ws;
    __hip_bfloat16* e_ws   = (__hip_bfloat16*)(ws);
    float*          Wh_ws  = (float*)(ws + 3145728);
    __hip_bfloat16* at_ws  = (__hip_bfloat16*)(ws + 9437184);
    __hip_bfloat16* Wb_ws  = (__hip_bfloat16*)(ws + 12582912);
    __hip_bfloat16* Pb_ws  = (__hip_bfloat16*)(ws + 13762560);
    __hip_bfloat16* Sb_ws  = (__hip_bfloat16*)(ws + 14942208);
    float*          s1_ws  = (float*)(ws + 16121856);
    float*          s2_ws  = (float*)(ws + 16187392);
    int*            cnt_ws = (int*)(ws + 16252928);
    int*            lst_ws = (int*)(ws + 16253056);

    prep_kernel<<<3264, 256, 0, stream>>>(eh, er, et, W_w, proj_w, skip_w,
                                          e_ws, Wb_ws, Pb_ws, Sb_ws, cnt_ws);

    // Wh = e @ W_w^T  (f32 output)
    gemm_nt_kernel<<<dim3(12, 32), 256, 0, stream>>>(
        e_ws, Wb_ws, 6, nullptr, nullptr, 0, nullptr, nullptr, Wh_ws);

    s12g_kernel<<<64, 256, 0, stream>>>(Wh_ws, a, s1_ws, s2_ws, h_id, cnt_ws, lst_ws);

    attn_kernel<<<512, 256, 0, stream>>>(Wh_ws, s1_ws, s2_ws, cnt_ws, lst_ws, at_ws);

    // out = at @ proj_w^T + e @ skip_w^T + (proj_b + skip_b)  (f32 output)
    gemm_nt_kernel<<<dim3(12, 32), 256, 0, stream>>>(
        at_ws, Pb_ws, 6, e_ws, Sb_ws, 6, proj_b, skip_b, out);
}